// Round 1
// baseline (345.718 us; speedup 1.0000x reference)
//
#include <hip/hip_runtime.h>
#include <math.h>

#define B    512
#define INU  8
#define IC   1152
#define NU   10
#define US   16
#define JU   160            // NU*US
#define KI   9216           // INU*IC
#define BETAC 1.45f

// ---------------------------------------------------------------------------
// build_M: M[ki, ju] = c[i,j] * W[i,j,u,k],  ki = k*IC + i, ju = j*16+u
// If c == nullptr, use uniform 1/IC (softmax of zeros, iteration 1).
// Grid: 1152 blocks (one per i) x 256 threads.
// ---------------------------------------------------------------------------
__global__ __launch_bounds__(256) void build_M_kernel(
    const float* __restrict__ W, const float* __restrict__ c,
    float* __restrict__ M) {
  int i = blockIdx.x;
  __shared__ float cj[NU];
  if (threadIdx.x < NU) {
    cj[threadIdx.x] = c ? c[i * NU + threadIdx.x] : (1.0f / (float)IC);
  }
  __syncthreads();
  for (int t = threadIdx.x; t < 1280; t += 256) {
    int j = t >> 7;          // t / 128
    int u = (t >> 3) & 15;
    int k = t & 7;
    M[(size_t)(k * IC + i) * JU + j * US + u] = W[(size_t)i * 1280 + t] * cj[j];
  }
}

// ---------------------------------------------------------------------------
// s_gemm: s_part[ks][b][ju] = sum_{ki in chunk ks} x[b,ki] * M[ki,ju]
// Grid: (16 b-tiles, nsplit) x 256 threads. Tile: 32 b x 160 ju, KT=32.
// Thread (tx,ty): b = b0 + ty*4 + ib (ib<4), ju = tx + 32*q (q<5).
// ---------------------------------------------------------------------------
__global__ __launch_bounds__(256) void s_gemm_kernel(
    const float* __restrict__ x, const float* __restrict__ M,
    float* __restrict__ s_part, int KC) {
  int b0 = blockIdx.x * 32;
  int kbase = blockIdx.y * KC;
  int t = threadIdx.x;
  int tx = t & 31, ty = t >> 5;
  __shared__ float xs[32 * 34];   // [b_local][kk], pad 34 -> conflict-free
  __shared__ float Ms[32 * JU];   // [kk][ju], 160 % 32 == 0 -> bank = ju%32
  float acc[4][5];
#pragma unroll
  for (int a = 0; a < 4; ++a)
#pragma unroll
    for (int q = 0; q < 5; ++q) acc[a][q] = 0.0f;

  for (int k0 = kbase; k0 < kbase + KC; k0 += 32) {
    __syncthreads();
#pragma unroll
    for (int r = 0; r < 4; ++r) {
      int idx = t + 256 * r;
      int bl = idx >> 5, kk = idx & 31;
      xs[bl * 34 + kk] = x[(size_t)(b0 + bl) * KI + k0 + kk];
    }
#pragma unroll
    for (int r = 0; r < 20; ++r) {
      int idx = t + 256 * r;
      int row = idx / JU;
      int col = idx - row * JU;
      Ms[row * JU + col] = M[(size_t)(k0 + row) * JU + col];
    }
    __syncthreads();
#pragma unroll
    for (int kk = 0; kk < 32; ++kk) {
      float xa[4], mv[5];
#pragma unroll
      for (int a = 0; a < 4; ++a) xa[a] = xs[(ty * 4 + a) * 34 + kk];
#pragma unroll
      for (int q = 0; q < 5; ++q) mv[q] = Ms[kk * JU + tx + 32 * q];
#pragma unroll
      for (int a = 0; a < 4; ++a)
#pragma unroll
        for (int q = 0; q < 5; ++q) acc[a][q] += xa[a] * mv[q];
    }
  }
#pragma unroll
  for (int a = 0; a < 4; ++a)
#pragma unroll
    for (int q = 0; q < 5; ++q)
      s_part[((size_t)blockIdx.y * B + b0 + ty * 4 + a) * JU + tx + 32 * q] =
          acc[a][q];
}

// ---------------------------------------------------------------------------
// squash: s[b,ju] = sum_ks s_part; msq[b,u] = sum_j s[b,j,u]^2 (axis=1 quirk,
// faithful to source); v = s * sqrt(msq)/(BETA+msq). Grid: 512 blocks x 192.
// ---------------------------------------------------------------------------
__global__ __launch_bounds__(192) void squash_kernel(
    const float* __restrict__ s_part, int nsplit, float* __restrict__ v,
    float* __restrict__ out) {
  int b = blockIdx.x;
  int t = threadIdx.x;
  __shared__ float sv[JU];
  __shared__ float fac[US];
  float s = 0.0f;
  if (t < JU) {
    for (int sp = 0; sp < nsplit; ++sp)
      s += s_part[((size_t)sp * B + b) * JU + t];
    sv[t] = s;
  }
  __syncthreads();
  if (t < US) {
    float m = 0.0f;
#pragma unroll
    for (int j = 0; j < NU; ++j) {
      float q = sv[j * US + t];
      m += q * q;
    }
    fac[t] = sqrtf(m) / (BETAC + m);
  }
  __syncthreads();
  if (t < JU) {
    float val = s * fac[t & 15];
    v[(size_t)b * JU + t] = val;
    if (out) out[(size_t)b * JU + t] = val;
  }
}

// ---------------------------------------------------------------------------
// b_update: R[ki,ju] = sum_b x[b,ki] v[b,ju];
// bij[i,j] = (1/B) sum_{u,k} W[i,j,u,k] * R[k*IC+i, j*16+u]
// Block covers one k, 32 consecutive i (coalesced x), half of b (split).
// Writes its own slice of bij_part[p= k*2+bsplit][i,j] -- no atomics.
// Grid: (288, 2) x 256 threads.
// ---------------------------------------------------------------------------
__global__ __launch_bounds__(256) void b_update_kernel(
    const float* __restrict__ x, const float* __restrict__ W,
    const float* __restrict__ v, float* __restrict__ bp) {
  int rowtile = blockIdx.x;       // 0..287 = 8 k * 36 i-tiles
  int k = rowtile / 36;
  int i0 = (rowtile - k * 36) * 32;
  int bs = blockIdx.y;            // 0..1
  int bc0 = bs * 256;
  int t = threadIdx.x;
  int tx = t & 31, ty = t >> 5;
  __shared__ float xs[32 * 34];   // [i_local][bb] padded
  __shared__ float vs[32 * JU];   // [bb][ju]
  __shared__ float Rs[32 * JU];   // [i_local][ju]
  float acc[4][5];
#pragma unroll
  for (int a = 0; a < 4; ++a)
#pragma unroll
    for (int q = 0; q < 5; ++q) acc[a][q] = 0.0f;

  for (int bc = bc0; bc < bc0 + 256; bc += 32) {
    __syncthreads();
#pragma unroll
    for (int r = 0; r < 4; ++r) {
      int idx = t + 256 * r;
      int bb = idx >> 5, il = idx & 31;
      xs[il * 34 + bb] = x[(size_t)(bc + bb) * KI + k * IC + i0 + il];
    }
#pragma unroll
    for (int r = 0; r < 20; ++r) {
      int idx = t + 256 * r;
      int row = idx / JU;
      int col = idx - row * JU;
      vs[row * JU + col] = v[(size_t)(bc + row) * JU + col];
    }
    __syncthreads();
#pragma unroll
    for (int bb = 0; bb < 32; ++bb) {
      float xa[4], vv[5];
#pragma unroll
      for (int a = 0; a < 4; ++a) xa[a] = xs[(ty * 4 + a) * 34 + bb];
#pragma unroll
      for (int q = 0; q < 5; ++q) vv[q] = vs[bb * JU + tx + 32 * q];
#pragma unroll
      for (int a = 0; a < 4; ++a)
#pragma unroll
        for (int q = 0; q < 5; ++q) acc[a][q] += xa[a] * vv[q];
    }
  }
  // stage R tile into LDS, then contract with W
#pragma unroll
  for (int a = 0; a < 4; ++a)
#pragma unroll
    for (int q = 0; q < 5; ++q)
      Rs[(ty * 4 + a) * JU + tx + 32 * q] = acc[a][q];
  __syncthreads();
  int p = k * 2 + bs;
  for (int o = t; o < 320; o += 256) {
    int il = o / 10;
    int j = o - il * 10;
    float sum = 0.0f;
#pragma unroll
    for (int u = 0; u < US; ++u)
      sum += W[(size_t)(i0 + il) * 1280 + j * 128 + u * 8 + k] *
             Rs[il * JU + j * US + u];
    bp[(size_t)p * (IC * NU) + (i0 + il) * NU + j] = sum * (1.0f / (float)B);
  }
}

// ---------------------------------------------------------------------------
// softmax over i (per j) of bij = sum of 16 partial slices.
// Grid: 10 blocks x 256 threads.
// ---------------------------------------------------------------------------
__global__ __launch_bounds__(256) void softmax_c_kernel(
    const float* __restrict__ bp, float* __restrict__ c) {
  int j = blockIdx.x;
  int t = threadIdx.x;
  __shared__ float bsum[IC];
  __shared__ float red[256];
  for (int i = t; i < IC; i += 256) {
    float s = 0.0f;
#pragma unroll
    for (int p = 0; p < 16; ++p) s += bp[(size_t)p * (IC * NU) + i * NU + j];
    bsum[i] = s;
  }
  __syncthreads();
  float m = -1e30f;
  for (int i = t; i < IC; i += 256) m = fmaxf(m, bsum[i]);
  red[t] = m;
  __syncthreads();
  for (int o = 128; o > 0; o >>= 1) {
    if (t < o) red[t] = fmaxf(red[t], red[t + o]);
    __syncthreads();
  }
  float mx = red[0];
  __syncthreads();
  float sm = 0.0f;
  for (int i = t; i < IC; i += 256) {
    float e = __expf(bsum[i] - mx);
    bsum[i] = e;
    sm += e;
  }
  red[t] = sm;
  __syncthreads();
  for (int o = 128; o > 0; o >>= 1) {
    if (t < o) red[t] += red[t + o];
    __syncthreads();
  }
  float inv = 1.0f / red[0];
  for (int i = t; i < IC; i += 256) c[i * NU + j] = bsum[i] * inv;
}

// ---------------------------------------------------------------------------
extern "C" void kernel_launch(void* const* d_in, const int* in_sizes, int n_in,
                              void* d_out, int out_size, void* d_ws,
                              size_t ws_size, hipStream_t stream) {
  const float* x = (const float*)d_in[0];   // (512, 8, 1152)
  const float* W = (const float*)d_in[1];   // (1152, 10, 16, 8)
  float* out = (float*)d_out;               // (512, 10, 16) flat

  float* ws = (float*)d_ws;
  // workspace layout (floats)
  float* c_buf = ws;                              // 11520
  float* M_buf = c_buf + (size_t)IC * NU;         // 1474560
  float* v_buf = M_buf + (size_t)KI * JU;         // 81920
  float* bp_buf = v_buf + (size_t)B * JU;         // 16 * 11520
  float* sp_buf = bp_buf + (size_t)16 * IC * NU;  // nsplit * 81920

  size_t base_floats = (size_t)IC * NU + (size_t)KI * JU + (size_t)B * JU +
                       (size_t)16 * IC * NU;
  int nsplit = 1;
  for (int cand = 32; cand >= 1; cand >>= 1) {
    if ((base_floats + (size_t)cand * B * JU) * sizeof(float) <= ws_size) {
      nsplit = cand;
      break;
    }
  }
  int KC = KI / nsplit;

  for (int it = 0; it < 3; ++it) {
    const float* c_arg;
    if (it == 0) {
      c_arg = nullptr;  // softmax of zero logits == uniform 1/IC
    } else {
      softmax_c_kernel<<<NU, 256, 0, stream>>>(bp_buf, c_buf);
      c_arg = c_buf;
    }
    build_M_kernel<<<IC, 256, 0, stream>>>(W, c_arg, M_buf);
    s_gemm_kernel<<<dim3(16, nsplit), 256, 0, stream>>>(x, M_buf, sp_buf, KC);
    squash_kernel<<<B, 192, 0, stream>>>(sp_buf, nsplit, v_buf,
                                         (it == 2) ? out : nullptr);
    if (it < 2) {
      b_update_kernel<<<dim3(288, 2), 256, 0, stream>>>(x, W, v_buf, bp_buf);
    }
  }
}

// Round 2
// 241.846 us; speedup vs baseline: 1.4295x; 1.4295x over previous
//
#include <hip/hip_runtime.h>
#include <math.h>

#define B    512
#define INU  8
#define IC   1152
#define NU   10
#define US   16
#define JU   160            // NU*US
#define KI   9216           // INU*IC
#define BETAC 1.45f

typedef __attribute__((ext_vector_type(8))) __bf16 bf16x8;
typedef __attribute__((ext_vector_type(4))) float floatx4;

static __device__ __forceinline__ unsigned short f2bf(float f) {
  unsigned u = __builtin_bit_cast(unsigned, f);
  u = (u + 0x7fffu + ((u >> 16) & 1u)) >> 16;   // RNE
  return (unsigned short)u;
}
static __device__ __forceinline__ float bf2f(unsigned short h) {
  return __builtin_bit_cast(float, ((unsigned)h) << 16);
}

// ---------------------------------------------------------------------------
// One-time: x (fp32 [b][ki]) -> xb bf16 [b][ki]  AND  xT bf16 [ki][b]
// 64x64 tiles via LDS (pad 65 -> conflict-free transpose).
// Grid: (144 ki-tiles, 8 b-tiles) x 256.
// ---------------------------------------------------------------------------
__global__ __launch_bounds__(256) void conv_transpose_x_kernel(
    const float* __restrict__ x, unsigned short* __restrict__ xb,
    unsigned short* __restrict__ xT) {
  int k0 = blockIdx.x * 64;
  int b0 = blockIdx.y * 64;
  __shared__ float ts[64 * 65];
  int t = threadIdx.x;
#pragma unroll
  for (int r = 0; r < 16; ++r) {
    int idx = t + 256 * r;
    int br = idx >> 6, kc = idx & 63;
    float v = x[(size_t)(b0 + br) * KI + k0 + kc];
    ts[br * 65 + kc] = v;
    xb[(size_t)(b0 + br) * KI + k0 + kc] = f2bf(v);
  }
  __syncthreads();
#pragma unroll
  for (int r = 0; r < 8; ++r) {
    int idx = t + 256 * r;            // 0..2047
    int kr = idx >> 5, bc = (idx & 31) * 2;
    unsigned lo = f2bf(ts[bc * 65 + kr]);
    unsigned hi = f2bf(ts[(bc + 1) * 65 + kr]);
    *(unsigned*)&xT[(size_t)(k0 + kr) * B + b0 + bc] = lo | (hi << 16);
  }
}

// ---------------------------------------------------------------------------
// One-time: Wt bf16 [ju][ki] = W[i,j,u,k],  ki=k*IC+i, ju=j*16+u.
// Coalesced writes; strided reads (L2-resident after warmup).
// ---------------------------------------------------------------------------
__global__ __launch_bounds__(256) void build_Wt_kernel(
    const float* __restrict__ W, unsigned short* __restrict__ Wt) {
  int e = blockIdx.x * 256 + threadIdx.x;   // < 1474560
  int ju = e / KI;
  int rem = e - ju * KI;
  int k = rem / IC;
  int i = rem - k * IC;
  Wt[e] = f2bf(W[(size_t)i * 1280 + ju * 8 + k]);
}

// ---------------------------------------------------------------------------
// Per-iter: Mt bf16 [ju][ki] = Wt * c[i,j]  (cT layout [j][i]; null -> 1/IC)
// Fully coalesced. Grid: 720 x 256, 8 elems/thread.
// ---------------------------------------------------------------------------
__global__ __launch_bounds__(256) void build_Mt_kernel(
    const unsigned short* __restrict__ Wt, const float* __restrict__ cT,
    unsigned short* __restrict__ Mt) {
  int ch = blockIdx.x * 256 + threadIdx.x;  // chunk of 8
  int e = ch * 8;
  int ju = e / KI;
  int rem = e - ju * KI;
  int k = rem / IC;
  int i = rem - k * IC;
  int j = ju >> 4;
  (void)k;
  unsigned short o[8];
  if (cT) {
    const float* cp = cT + (size_t)j * IC + i;
#pragma unroll
    for (int m = 0; m < 8; ++m) o[m] = f2bf(bf2f(Wt[e + m]) * cp[m]);
  } else {
    const float cu = 1.0f / (float)IC;
#pragma unroll
    for (int m = 0; m < 8; ++m) o[m] = f2bf(bf2f(Wt[e + m]) * cu);
  }
  *(uint4*)&Mt[e] = *(uint4*)o;
}

// ---------------------------------------------------------------------------
// s_gemm (MFMA): sp[ks][b][ju] = sum_{ki chunk} xb[b,ki] * Mt[ju,ki]
// Block: 256 thr = 4 waves; tile 64 b x 160 ju; wave = 16 b x 160 ju
// (10 MFMA 16x16x32 per K-step of 32). Grid: (8, nsplit).
// ---------------------------------------------------------------------------
__global__ __launch_bounds__(256) void s_gemm_mfma(
    const unsigned short* __restrict__ xb, const unsigned short* __restrict__ Mt,
    float* __restrict__ sp, int KC) {
  int b0 = blockIdx.x * 64;
  int kbase = blockIdx.y * KC;
  int t = threadIdx.x;
  int w = t >> 6, lane = t & 63, col = lane & 15, quad = lane >> 4;
  __shared__ unsigned short xs[64 * 40];    // pad 40: <=2-way (free)
  __shared__ unsigned short ms[160 * 40];
  floatx4 acc[10];
#pragma unroll
  for (int jt = 0; jt < 10; ++jt) acc[jt] = (floatx4){0.f, 0.f, 0.f, 0.f};

  for (int k0 = kbase; k0 < kbase + KC; k0 += 32) {
    __syncthreads();
    {
      int row = t >> 2, c8 = (t & 3) * 8;
      *(uint4*)&xs[row * 40 + c8] =
          *(const uint4*)&xb[(size_t)(b0 + row) * KI + k0 + c8];
    }
#pragma unroll
    for (int ch = t; ch < 640; ch += 256) {
      int row = ch >> 2, c8 = (ch & 3) * 8;
      *(uint4*)&ms[row * 40 + c8] =
          *(const uint4*)&Mt[(size_t)row * KI + k0 + c8];
    }
    __syncthreads();
    bf16x8 a = *(bf16x8*)&xs[(w * 16 + col) * 40 + quad * 8];
#pragma unroll
    for (int jt = 0; jt < 10; ++jt) {
      bf16x8 bb = *(bf16x8*)&ms[(jt * 16 + col) * 40 + quad * 8];
      acc[jt] = __builtin_amdgcn_mfma_f32_16x16x32_bf16(a, bb, acc[jt], 0, 0, 0);
    }
  }
#pragma unroll
  for (int jt = 0; jt < 10; ++jt)
#pragma unroll
    for (int r = 0; r < 4; ++r) {
      int b = b0 + w * 16 + quad * 4 + r;
      sp[((size_t)blockIdx.y * B + b) * JU + jt * 16 + col] = acc[jt][r];
    }
}

// ---------------------------------------------------------------------------
// squash: s[b][ju] = sum_ks sp; msq over j (axis=1 quirk, faithful);
// v -> vT bf16 [ju][b]; out fp32 on last iter. Grid: 512 x 192.
// ---------------------------------------------------------------------------
__global__ __launch_bounds__(192) void squash_kernel(
    const float* __restrict__ sp, int nsplit, unsigned short* __restrict__ vT,
    float* __restrict__ out) {
  int b = blockIdx.x;
  int t = threadIdx.x;
  __shared__ float sv[JU];
  __shared__ float fac[US];
  float s = 0.0f;
  if (t < JU) {
    for (int k = 0; k < nsplit; ++k) s += sp[((size_t)k * B + b) * JU + t];
    sv[t] = s;
  }
  __syncthreads();
  if (t < US) {
    float m = 0.0f;
#pragma unroll
    for (int j = 0; j < NU; ++j) {
      float q = sv[j * US + t];
      m += q * q;
    }
    fac[t] = sqrtf(m) / (BETAC + m);
  }
  __syncthreads();
  if (t < JU) {
    float val = s * fac[t & 15];
    vT[(size_t)t * B + b] = f2bf(val);
    if (out) out[(size_t)b * JU + t] = val;
  }
}

// ---------------------------------------------------------------------------
// b_update (MFMA): R[ki,ju] = sum_b xT[ki,b] * vT[ju,b]  (K = b, split 2);
// then bij partial = (1/B) sum_u W[i,j,u,k]*R via 16-lane shfl reduce
// (C-layout: u = lane&15). Writes bp slice p = k*2+bs. Grid: (144,2).
// ---------------------------------------------------------------------------
__global__ __launch_bounds__(256) void b_update_mfma(
    const unsigned short* __restrict__ xT, const unsigned short* __restrict__ vT,
    const float* __restrict__ W, float* __restrict__ bp) {
  int k = blockIdx.x / 18;
  int i0 = (blockIdx.x - k * 18) * 64;
  int bs = blockIdx.y;
  size_t ki0 = (size_t)k * IC + i0;
  int t = threadIdx.x;
  int w = t >> 6, lane = t & 63, col = lane & 15, quad = lane >> 4;
  __shared__ unsigned short xs[64 * 40];
  __shared__ unsigned short vs[160 * 40];
  floatx4 acc[10];
#pragma unroll
  for (int jt = 0; jt < 10; ++jt) acc[jt] = (floatx4){0.f, 0.f, 0.f, 0.f};

  for (int c0 = bs * 256; c0 < bs * 256 + 256; c0 += 32) {
    __syncthreads();
    {
      int row = t >> 2, c8 = (t & 3) * 8;
      *(uint4*)&xs[row * 40 + c8] =
          *(const uint4*)&xT[(ki0 + row) * B + c0 + c8];
    }
#pragma unroll
    for (int ch = t; ch < 640; ch += 256) {
      int row = ch >> 2, c8 = (ch & 3) * 8;
      *(uint4*)&vs[row * 40 + c8] =
          *(const uint4*)&vT[(size_t)row * B + c0 + c8];
    }
    __syncthreads();
    bf16x8 a = *(bf16x8*)&xs[(w * 16 + col) * 40 + quad * 8];
#pragma unroll
    for (int jt = 0; jt < 10; ++jt) {
      bf16x8 bb = *(bf16x8*)&vs[(jt * 16 + col) * 40 + quad * 8];
      acc[jt] = __builtin_amdgcn_mfma_f32_16x16x32_bf16(a, bb, acc[jt], 0, 0, 0);
    }
  }
  int p = k * 2 + bs;
#pragma unroll
  for (int jt = 0; jt < 10; ++jt) {
#pragma unroll
    for (int r = 0; r < 4; ++r) {
      int i = i0 + w * 16 + quad * 4 + r;
      float wv = W[(size_t)i * 1280 + jt * 128 + col * 8 + k];
      float pr = wv * acc[jt][r];
      pr += __shfl_xor(pr, 1);
      pr += __shfl_xor(pr, 2);
      pr += __shfl_xor(pr, 4);
      pr += __shfl_xor(pr, 8);
      if (col == 0)
        bp[(size_t)p * (IC * NU) + (size_t)i * NU + jt] = pr * (1.0f / (float)B);
    }
  }
}

// ---------------------------------------------------------------------------
// softmax over i (per j) of bij = sum of 16 partial slices -> cT[j][i].
// Grid: 10 x 256.
// ---------------------------------------------------------------------------
__global__ __launch_bounds__(256) void softmax_c_kernel(
    const float* __restrict__ bp, float* __restrict__ cT) {
  int j = blockIdx.x;
  int t = threadIdx.x;
  __shared__ float bsum[IC];
  __shared__ float red[256];
  for (int i = t; i < IC; i += 256) {
    float s = 0.0f;
#pragma unroll
    for (int p = 0; p < 16; ++p) s += bp[(size_t)p * (IC * NU) + i * NU + j];
    bsum[i] = s;
  }
  __syncthreads();
  float m = -1e30f;
  for (int i = t; i < IC; i += 256) m = fmaxf(m, bsum[i]);
  red[t] = m;
  __syncthreads();
  for (int o = 128; o > 0; o >>= 1) {
    if (t < o) red[t] = fmaxf(red[t], red[t + o]);
    __syncthreads();
  }
  float mx = red[0];
  __syncthreads();
  float sm = 0.0f;
  for (int i = t; i < IC; i += 256) {
    float e = __expf(bsum[i] - mx);
    bsum[i] = e;
    sm += e;
  }
  red[t] = sm;
  __syncthreads();
  for (int o = 128; o > 0; o >>= 1) {
    if (t < o) red[t] += red[t + o];
    __syncthreads();
  }
  float inv = 1.0f / red[0];
  for (int i = t; i < IC; i += 256) cT[(size_t)j * IC + i] = bsum[i] * inv;
}

// ---------------------------------------------------------------------------
extern "C" void kernel_launch(void* const* d_in, const int* in_sizes, int n_in,
                              void* d_out, int out_size, void* d_ws,
                              size_t ws_size, hipStream_t stream) {
  const float* x = (const float*)d_in[0];   // (512, 8, 1152)
  const float* W = (const float*)d_in[1];   // (1152, 10, 16, 8)
  float* out = (float*)d_out;               // (512, 10, 16)

  // fixed workspace pieces (bytes, all 16B-aligned sizes)
  const size_t n_cT = (size_t)NU * IC;            // fp32
  const size_t n_bp = (size_t)16 * IC * NU;       // fp32
  const size_t n_xb = (size_t)B * KI;             // bf16
  const size_t n_xT = (size_t)KI * B;             // bf16
  const size_t n_Wt = (size_t)JU * KI;            // bf16
  const size_t n_Mt = (size_t)JU * KI;            // bf16
  const size_t n_vT = (size_t)JU * B;             // bf16
  const size_t fixed_bytes =
      (n_cT + n_bp) * 4 + (n_xb + n_xT + n_Wt + n_Mt + n_vT) * 2;

  // nsplit must divide 288 (k-steps of 32)
  static const int cands[] = {36, 32, 24, 18, 16, 12, 9, 8, 6, 4, 3, 2, 1};
  int nsplit = 1;
  for (int ci = 0; ci < 13; ++ci) {
    size_t need = fixed_bytes + (size_t)cands[ci] * B * JU * 4;
    if (need <= ws_size) { nsplit = cands[ci]; break; }
  }
  int KC = KI / nsplit;

  char* p = (char*)d_ws;
  float* cT = (float*)p;            p += n_cT * 4;
  float* bp = (float*)p;            p += n_bp * 4;
  float* sp = (float*)p;            p += (size_t)nsplit * B * JU * 4;
  unsigned short* xb = (unsigned short*)p;  p += n_xb * 2;
  unsigned short* xT = (unsigned short*)p;  p += n_xT * 2;
  unsigned short* Wt = (unsigned short*)p;  p += n_Wt * 2;
  unsigned short* Mt = (unsigned short*)p;  p += n_Mt * 2;
  unsigned short* vT = (unsigned short*)p;

  conv_transpose_x_kernel<<<dim3(KI / 64, B / 64), 256, 0, stream>>>(x, xb, xT);
  build_Wt_kernel<<<(JU * KI) / 256, 256, 0, stream>>>(W, Wt);

  for (int it = 0; it < 3; ++it) {
    const float* c_arg = nullptr;
    if (it > 0) {
      softmax_c_kernel<<<NU, 256, 0, stream>>>(bp, cT);
      c_arg = cT;
    }
    build_Mt_kernel<<<(JU * KI) / (256 * 8), 256, 0, stream>>>(Wt, c_arg, Mt);
    s_gemm_mfma<<<dim3(8, nsplit), 256, 0, stream>>>(xb, Mt, sp, KC);
    squash_kernel<<<B, 192, 0, stream>>>(sp, nsplit, vT,
                                         (it == 2) ? out : nullptr);
    if (it < 2) {
      b_update_mfma<<<dim3(144, 2), 256, 0, stream>>>(xT, vT, W, bp);
    }
  }
}